// Round 2
// baseline (1306.085 us; speedup 1.0000x reference)
//
#include <hip/hip_runtime.h>

#define OUT_STRIDE 480

__device__ __forceinline__ float dot4acc(float4 a, float4 b, float acc) {
  acc = fmaf(a.x, b.x, acc);
  acc = fmaf(a.y, b.y, acc);
  acc = fmaf(a.z, b.z, acc);
  acc = fmaf(a.w, b.w, acc);
  return acc;
}

// Tiled register-blocked GEMM per irrep.
//   y[t, o, m] = sum_i x[t, i, m] * w[o, i, m]
// Wave tile: (8*TO) o  x  (8*TT) t ; per-lane tile TO x TT x M accumulators.
// LDS: double-buffered k-chunks, m-deinterleaved planes, row stride RS ≡ 4 (mod 8)
// words => 16B-aligned AND bank-conflict-free ds_read_b128 with the
// lane-interleaved mapping t = j*8 + lane_t, o = jo*8 + lane_o.
template<int MUL, int M, int OBLK, int WAVES_O, int TO, int TT, int IC, int OUT_OFF, bool HAS_BIAS>
__global__ __launch_bounds__(256, 2) void lin_kernel(
    const float* __restrict__ x, const float* __restrict__ w,
    const float* __restrict__ bias, float* __restrict__ out, int n_nodes)
{
  constexpr int K = MUL;                 // reduction length
  constexpr int R = K * M;               // floats per node row (this irrep)
  constexpr int CF = IC * M;             // chunk floats per row
  constexpr int C4 = CF / 4;             // float4s per row-chunk
  constexpr int RS = (IC % 8 == 4) ? IC : IC + 4;  // LDS row stride (words)
  constexpr int WAVES_T = 4 / WAVES_O;
  constexpr int TROW = 8 * TT;           // nodes per wave
  constexpr int TTILE = WAVES_T * TROW;  // nodes per block
  constexpr int CHUNKS = K / IC;
  constexpr int XPLANE = TTILE * RS;
  constexpr int XSZ = M * XPLANE;
  constexpr int WPLANE = OBLK * RS;
  constexpr int WSZ = M * WPLANE;
  constexpr int NX4 = TTILE * CF / 4;
  constexpr int NW4 = OBLK * CF / 4;
  constexpr int XLD = (NX4 + 255) / 256;
  constexpr int WLD = (NW4 + 255) / 256;

  __shared__ float xs[2 * XSZ];
  __shared__ float ws[2 * WSZ];

  const int tid = threadIdx.x;
  const int lane = tid & 63;
  const int wv = tid >> 6;
  const int lane_o = lane & 7;
  const int lane_t = lane >> 3;
  const int wo = (WAVES_O > 1) ? (wv % WAVES_O) : 0;
  const int tr = wv / WAVES_O;

  const int blk_t0 = blockIdx.x * TTILE;
  const int o_grid = blockIdx.y * OBLK;

  float4 xr[XLD];
  float4 wr[WLD];

  auto load_chunk = [&](int c) {
#pragma unroll
    for (int l = 0; l < XLD; ++l) {
      int idx = tid + l * 256;
      if (XLD * 256 == NX4 || idx < NX4) {
        int t = idx / C4, q = idx - t * C4;
        int gt = blk_t0 + t;
        if (gt < n_nodes)
          xr[l] = *(const float4*)(x + (size_t)gt * R + c * CF + q * 4);
        else
          xr[l] = make_float4(0.f, 0.f, 0.f, 0.f);
      }
    }
#pragma unroll
    for (int l = 0; l < WLD; ++l) {
      int idx = tid + l * 256;
      if (WLD * 256 == NW4 || idx < NW4) {
        int o = idx / C4, q = idx - o * C4;
        wr[l] = *(const float4*)(w + (size_t)(o_grid + o) * R + c * CF + q * 4);
      }
    }
  };

  auto write_chunk = [&](int buf) {
    float* xb = xs + buf * XSZ;
    float* wb = ws + buf * WSZ;
#pragma unroll
    for (int l = 0; l < XLD; ++l) {
      int idx = tid + l * 256;
      if (XLD * 256 == NX4 || idx < NX4) {
        int t = idx / C4, q = idx - t * C4;
        if (M == 1) {
          *(float4*)(xb + t * RS + q * 4) = xr[l];
        } else {
          float v[4] = {xr[l].x, xr[l].y, xr[l].z, xr[l].w};
#pragma unroll
          for (int e = 0; e < 4; ++e) {
            int off = q * 4 + e;
            int i = off / M, m = off - i * M;
            xb[m * XPLANE + t * RS + i] = v[e];
          }
        }
      }
    }
#pragma unroll
    for (int l = 0; l < WLD; ++l) {
      int idx = tid + l * 256;
      if (WLD * 256 == NW4 || idx < NW4) {
        int o = idx / C4, q = idx - o * C4;
        if (M == 1) {
          *(float4*)(wb + o * RS + q * 4) = wr[l];
        } else {
          float v[4] = {wr[l].x, wr[l].y, wr[l].z, wr[l].w};
#pragma unroll
          for (int e = 0; e < 4; ++e) {
            int off = q * 4 + e;
            int i = off / M, m = off - i * M;
            wb[m * WPLANE + o * RS + i] = v[e];
          }
        }
      }
    }
  };

  float acc[M][TO][TT];
#pragma unroll
  for (int m = 0; m < M; ++m)
#pragma unroll
    for (int jo = 0; jo < TO; ++jo)
#pragma unroll
      for (int j = 0; j < TT; ++j) acc[m][jo][j] = 0.f;

  load_chunk(0);
  write_chunk(0);
  __syncthreads();

  for (int c = 0; c < CHUNKS; ++c) {
    if (c + 1 < CHUNKS) load_chunk(c + 1);  // VMEM in flight during compute
    const int buf = c & 1;
    const float* xbase = xs + buf * XSZ + (tr * TROW) * RS;
    const float* wbase = ws + buf * WSZ + (wo * 8 * TO) * RS;
#pragma unroll
    for (int i4 = 0; i4 < IC / 4; ++i4) {
#pragma unroll
      for (int m = 0; m < M; ++m) {
        const float* xp = xbase + m * XPLANE + i4 * 4;
        const float* wp = wbase + m * WPLANE + i4 * 4;
        float4 xf[TT];
#pragma unroll
        for (int j = 0; j < TT; ++j)
          xf[j] = *(const float4*)(xp + (j * 8 + lane_t) * RS);
        float4 wf[TO];
#pragma unroll
        for (int jo = 0; jo < TO; ++jo)
          wf[jo] = *(const float4*)(wp + (jo * 8 + lane_o) * RS);
#pragma unroll
        for (int jo = 0; jo < TO; ++jo)
#pragma unroll
          for (int j = 0; j < TT; ++j)
            acc[m][jo][j] = dot4acc(xf[j], wf[jo], acc[m][jo][j]);
      }
    }
    if (c + 1 < CHUNKS) write_chunk((c + 1) & 1);
    __syncthreads();
  }

  // ---- epilogue ----
  float bv[TO];
  if (HAS_BIAS) {
#pragma unroll
    for (int jo = 0; jo < TO; ++jo)
      bv[jo] = bias[o_grid + wo * 8 * TO + jo * 8 + lane_o];
  }
#pragma unroll
  for (int j = 0; j < TT; ++j) {
    int t = blk_t0 + tr * TROW + j * 8 + lane_t;
    if (t < n_nodes) {
#pragma unroll
      for (int jo = 0; jo < TO; ++jo) {
        int o = o_grid + wo * 8 * TO + jo * 8 + lane_o;
#pragma unroll
        for (int m = 0; m < M; ++m) {
          float v = acc[m][jo][j];
          if (HAS_BIAS) v += bv[jo];
          out[(size_t)t * OUT_STRIDE + OUT_OFF + o * M + m] = v;
        }
      }
    }
  }
}

extern "C" void kernel_launch(void* const* d_in, const int* in_sizes, int n_in,
                              void* d_out, int out_size, void* d_ws, size_t ws_size,
                              hipStream_t stream) {
  const float* x0e = (const float*)d_in[0];
  const float* x1o = (const float*)d_in[1];
  const float* x2e = (const float*)d_in[2];
  const float* w0e = (const float*)d_in[3];
  const float* w1o = (const float*)d_in[4];
  const float* w2e = (const float*)d_in[5];
  const float* bias = (const float*)d_in[6];
  float* out = (float*)d_out;

  const int n = in_sizes[0] / 128;  // N nodes

  dim3 blk(256);

  // 0e: MUL=128, M=1. Block tile 64 o x 256 t, o split over grid.y (2 halves).
  // LDS 50 KB -> 3 blocks/CU. acc 64, chunks=8 (IC=16).
  dim3 g0((n + 255) / 256, 2);
  lin_kernel<128, 1, 64, 1, 8, 8, 16, 0, true>
      <<<g0, blk, 0, stream>>>(x0e, w0e, bias, out, n);

  // 1o: MUL=64, M=3. Block tile 64 o x 128 t (2 o-cols x 2 t-rows).
  // LDS 55 KB -> 2 blocks/CU. acc 3*4*8=96, chunks=8 (IC=8).
  dim3 g1((n + 127) / 128, 1);
  lin_kernel<64, 3, 64, 2, 4, 8, 8, 128, false>
      <<<g1, blk, 0, stream>>>(x1o, w1o, nullptr, out, n);

  // 2e: MUL=32, M=5. Block tile 32 o x 128 t (4 t-rows of 32).
  // LDS 25 KB. acc 5*4*4=80, chunks=8 (IC=4).
  lin_kernel<32, 5, 32, 1, 4, 4, 4, 320, false>
      <<<g1, blk, 0, stream>>>(x2e, w2e, nullptr, out, n);
}